// Round 5
// baseline (262.293 us; speedup 1.0000x reference)
//
#include <hip/hip_runtime.h>
#include <hip/hip_bf16.h>
#include <cstdint>
#include <cstddef>

// MFMA fragment types (gfx950: V8y operands, V4f accumulator)
typedef __bf16 v8bf __attribute__((ext_vector_type(8)));
typedef float  v4f  __attribute__((ext_vector_type(4)));

__device__ __forceinline__ unsigned short f2bf(float f) {
    unsigned int u = __float_as_uint(f);
    u += 0x7fffu + ((u >> 16) & 1u);   // round-to-nearest-even
    return (unsigned short)(u >> 16);
}

// async global->LDS, 16B per lane. LDS deposit is wave-uniform base + lane*16;
// the GLOBAL source address is per-lane.
__device__ __forceinline__ void gload_lds16(const unsigned short* g, unsigned short* l) {
    __builtin_amdgcn_global_load_lds(
        (const __attribute__((address_space(1))) unsigned int*)(uintptr_t)g,
        (__attribute__((address_space(3))) unsigned int*)(uintptr_t)l, 16, 0, 0);
}

// ---------------------------------------------------------------------------
// Legacy 128x128 GEMM (kept only for the small Wfold GEMM, 128 blocks).
// C[M,N] = A[M,K] * B[K,N], B transposed (BT is N x K). bf16 in, fp32 acc.
// ---------------------------------------------------------------------------
template<int WRITE_BF16>
__global__ __launch_bounds__(256, 2) void gemm_bt(
    const unsigned short* __restrict__ A,   // M x K, row stride lda (bf16)
    const unsigned short* __restrict__ BT,  // N x K, row stride ldb (bf16)
    void* __restrict__ C,                   // M x N, row stride ldc
    int K, int lda, int ldb, int ldc,
    size_t sAz, size_t sBz, size_t sCz,     // per-z strides (elements)
    int nBlk, int mPerXcd)
{
    __shared__ unsigned short sA[128 * 32];
    __shared__ unsigned short sB[128 * 32];

    const int id = blockIdx.x;
    const int xcd = id & 7;
    int s = id >> 3;
    const int perXcd = mPerXcd * nBlk;
    const int z = s / perXcd;
    s -= z * perXcd;
    const int mB = xcd * mPerXcd + s / nBlk;
    const int nB = s - (s / nBlk) * nBlk;

    const unsigned short* Ab = A + (size_t)z * sAz;
    const unsigned short* Bb = BT + (size_t)z * sBz;

    const int tid  = threadIdx.x;
    const int wv   = tid >> 6;
    const int lane = tid & 63;
    const int quad = lane >> 4;
    const int l16  = lane & 15;
    const size_t bm = (size_t)mB * 128;
    const size_t bn = (size_t)nB * 128;
    const int wm = (wv >> 1) * 64;
    const int wn = (wv & 1) * 64;

    const int ro = tid >> 2;
    const int ko = (((tid & 3) ^ (ro & 3)) << 3);

    const unsigned short* aptr0 = Ab + (bm + ro)      * (size_t)lda + ko;
    const unsigned short* aptr1 = Ab + (bm + ro + 64) * (size_t)lda + ko;
    const unsigned short* bptr0 = Bb + (bn + ro)      * (size_t)ldb + ko;
    const unsigned short* bptr1 = Bb + (bn + ro + 64) * (size_t)ldb + ko;

    unsigned short* sA0 = &sA[wv * 512];
    unsigned short* sA1 = &sA[2048 + wv * 512];
    unsigned short* sB0 = &sB[wv * 512];
    unsigned short* sB1 = &sB[2048 + wv * 512];

    const int sslot = ((quad ^ (l16 & 3)) << 3);

    v4f acc[4][4] = {};

    for (int k0 = 0; k0 < K; k0 += 32) {
        gload_lds16(aptr0 + k0, sA0);
        gload_lds16(aptr1 + k0, sA1);
        gload_lds16(bptr0 + k0, sB0);
        gload_lds16(bptr1 + k0, sB1);
        __syncthreads();

        v8bf af[4], bfr[4];
        #pragma unroll
        for (int t = 0; t < 4; t++) {
            af[t]  = *(const v8bf*)&sA[(size_t)(wm + t * 16 + l16) * 32 + sslot];
            bfr[t] = *(const v8bf*)&sB[(size_t)(wn + t * 16 + l16) * 32 + sslot];
        }

        #pragma unroll
        for (int ti = 0; ti < 4; ti++)
            #pragma unroll
            for (int tj = 0; tj < 4; tj++)
                acc[ti][tj] = __builtin_amdgcn_mfma_f32_16x16x32_bf16(
                    af[ti], bfr[tj], acc[ti][tj], 0, 0, 0);
        __syncthreads();
    }

    if (WRITE_BF16) {
        unsigned short* Cb = (unsigned short*)C + (size_t)z * sCz;
        #pragma unroll
        for (int ti = 0; ti < 4; ti++) {
            const size_t row0 = bm + wm + ti * 16 + quad * 4;
            #pragma unroll
            for (int tj = 0; tj < 4; tj++) {
                const size_t col = bn + wn + tj * 16 + l16;
                #pragma unroll
                for (int r = 0; r < 4; r++)
                    Cb[(row0 + r) * (size_t)ldc + col] = f2bf(acc[ti][tj][r]);
            }
        }
    } else {
        float* Cb = (float*)C + (size_t)z * sCz;
        #pragma unroll
        for (int ti = 0; ti < 4; ti++) {
            const size_t row0 = bm + wm + ti * 16 + quad * 4;
            #pragma unroll
            for (int tj = 0; tj < 4; tj++) {
                const size_t col = bn + wn + tj * 16 + l16;
                #pragma unroll
                for (int r = 0; r < 4; r++)
                    Cb[(row0 + r) * (size_t)ldc + col] = acc[ti][tj][r];
            }
        }
    }
}

// ---------------------------------------------------------------------------
// 256x256-tile, BK=64, 8-wave (2Mx4N), 8-phase GEMM with counted vmcnt.
// ROUND-5: round-1 schedule (measured best 44.2us: barrier + asm lgkmcnt(0)
// + MFMA, no sched_barrier) PLUS one isolated change: ph4 reads B(nh0) of
// tile t+1 (after vmcnt(6) proves it landed) into double-banked b0a/b0b,
// rebalancing ds_read phases 12/4/8/0 -> 8/4/8/4.  History:
//   r1 template port            44.2 us  (best)
//   r2 +sched_barrier+early-rd  49.0 us  (sched_barrier bad, m141)
//   r4 -lgkm0,+consume-order    51.3 us  (explicit lgkm0 is load-bearing)
// Phase map per K-tile t (P = t&1, steady state):
//   ph1: rd A(mh0)x8            ; stage A1(t+1)->bufP^1 ; bar;lgkm0; MFMA(0,0)[b0cur]; bar
//   ph2: rd B(nh1)x4            ; stage A0(t+2)->bufP   ; bar;lgkm0; MFMA(0,1)[b1]  ; bar
//   ph3: rd A(mh1)x8            ; stage B0(t+2)->bufP   ; bar;lgkm0; MFMA(1,1)[b1]  ; bar
//   ph4: stage B1(t+2); vmcnt(6); rd B0(t+1)x4 -> b0nxt ; bar;       MFMA(1,0)[b0cur]; bar
// vmcnt audit: 6 outstanding entering t ({A0,B0,B1}(t+1)); +2/phase -> 14 at
// ph4's vmcnt(6), draining {A0,B0,B1,A1}(t+1) -> tile t+1 fully landed before
// its ph4 early-read and its ph1 reads.  Early-read drain: consumed by next
// tile's MFMA(0,0) behind that ph1's lgkm0; region re-staged only in tile
// t+1's ph3 (two barriers later).  NT even, >= 2.
// ---------------------------------------------------------------------------
#define MFMA_Q(MH, NH, BF)                                                    \
    do {                                                                      \
        __builtin_amdgcn_s_setprio(1);                                        \
        _Pragma("unroll")                                                     \
        for (int mi = 0; mi < 4; ++mi) {                                      \
            _Pragma("unroll")                                                 \
            for (int ni = 0; ni < 2; ++ni) {                                  \
                acc[(MH)*4 + mi][(NH)*2 + ni] =                               \
                    __builtin_amdgcn_mfma_f32_16x16x32_bf16(                  \
                        aF[mi][0], BF[ni][0],                                 \
                        acc[(MH)*4 + mi][(NH)*2 + ni], 0, 0, 0);              \
                acc[(MH)*4 + mi][(NH)*2 + ni] =                               \
                    __builtin_amdgcn_mfma_f32_16x16x32_bf16(                  \
                        aF[mi][1], BF[ni][1],                                 \
                        acc[(MH)*4 + mi][(NH)*2 + ni], 0, 0, 0);              \
            }                                                                 \
        }                                                                     \
        __builtin_amdgcn_s_setprio(0);                                        \
    } while (0)

#define GTILE(T, P, B0CUR, B0NXT)                                             \
    do {                                                                      \
        const unsigned short* sa = sm + (P) * 16384;                          \
        const unsigned short* sb = sm + 32768 + (P) * 16384;                  \
        unsigned short* dq = sm + ((P) ^ 1) * 16384;                          \
        unsigned short* dp = sm + (P) * 16384;                                \
        const int kk1 = ((T) + 1) * 64, kk2 = ((T) + 2) * 64;                 \
        /* ---- phase 1: rd A(mh0); stage A1(t+1) ---- */                     \
        _Pragma("unroll")                                                     \
        for (int mi = 0; mi < 4; ++mi) {                                      \
            aF[mi][0] = *(const v8bf*)(sa + (arow0 + mi * 1024));             \
            aF[mi][1] = *(const v8bf*)(sa + ((arow0 + mi * 1024) ^ 32));      \
        }                                                                     \
        if ((T) + 1 < NT) {                                                   \
            gload_lds16(aP + 128 * lda + kk1, dq + 8192 + stA);               \
            gload_lds16(aP + 192 * lda + kk1, dq + 8192 + stA + 4096);        \
        }                                                                     \
        __builtin_amdgcn_s_barrier();                                         \
        asm volatile("s_waitcnt lgkmcnt(0)" ::: "memory");                    \
        MFMA_Q(0, 0, B0CUR);                                                  \
        __builtin_amdgcn_s_barrier();                                         \
        /* ---- phase 2: rd B(nh1); stage A0(t+2) ---- */                     \
        _Pragma("unroll")                                                     \
        for (int ni = 0; ni < 2; ++ni) {                                      \
            b1[ni][0] = *(const v8bf*)(sb + 8192 + (brow0 + ni * 1024));      \
            b1[ni][1] = *(const v8bf*)(sb + 8192 + ((brow0 + ni * 1024) ^ 32));\
        }                                                                     \
        if ((T) + 2 < NT) {                                                   \
            gload_lds16(aP + kk2,            dp + stA);                       \
            gload_lds16(aP + 64 * lda + kk2, dp + stA + 4096);                \
        }                                                                     \
        __builtin_amdgcn_s_barrier();                                         \
        asm volatile("s_waitcnt lgkmcnt(0)" ::: "memory");                    \
        MFMA_Q(0, 1, b1);                                                     \
        __builtin_amdgcn_s_barrier();                                         \
        /* ---- phase 3: rd A(mh1); stage B0(t+2) ---- */                     \
        _Pragma("unroll")                                                     \
        for (int mi = 0; mi < 4; ++mi) {                                      \
            aF[mi][0] = *(const v8bf*)(sa + 8192 + (arow0 + mi * 1024));      \
            aF[mi][1] = *(const v8bf*)(sa + 8192 + ((arow0 + mi * 1024) ^ 32));\
        }                                                                     \
        if ((T) + 2 < NT) {                                                   \
            gload_lds16(bP + kk2,            dp + 32768 + stA);               \
            gload_lds16(bP + 64 * ldb + kk2, dp + 32768 + stA + 4096);        \
        }                                                                     \
        __builtin_amdgcn_s_barrier();                                         \
        asm volatile("s_waitcnt lgkmcnt(0)" ::: "memory");                    \
        MFMA_Q(1, 1, b1);                                                     \
        __builtin_amdgcn_s_barrier();                                         \
        /* ---- phase 4: stage B1(t+2); vmcnt(6); early-rd B0(t+1) ---- */    \
        if ((T) + 2 < NT) {                                                   \
            gload_lds16(bP + 128 * ldb + kk2, dp + 32768 + 8192 + stA);       \
            gload_lds16(bP + 192 * ldb + kk2, dp + 32768 + 8192 + stA + 4096);\
            asm volatile("s_waitcnt vmcnt(6)" ::: "memory");                  \
        } else {                                                              \
            asm volatile("s_waitcnt vmcnt(0)" ::: "memory");                  \
        }                                                                     \
        if ((T) + 1 < NT) {                                                   \
            const unsigned short* nb = sm + 32768 + ((P) ^ 1) * 16384;        \
            _Pragma("unroll")                                                 \
            for (int ni = 0; ni < 2; ++ni) {                                  \
                B0NXT[ni][0] = *(const v8bf*)(nb + (brow0 + ni * 1024));      \
                B0NXT[ni][1] = *(const v8bf*)(nb + ((brow0 + ni * 1024) ^ 32));\
            }                                                                 \
            asm volatile("" ::: "memory");                                    \
        }                                                                     \
        __builtin_amdgcn_s_barrier();                                         \
        MFMA_Q(1, 0, B0CUR);                                                  \
        __builtin_amdgcn_s_barrier();                                         \
    } while (0)

template<int WRITE_BF16>
__global__ __launch_bounds__(512, 2) void gemm256_bt(
    const unsigned short* __restrict__ A,   // M x K (bf16), row stride lda
    const unsigned short* __restrict__ BT,  // N x K (bf16), row stride ldb
    void* __restrict__ C,                   // M x N, row stride ldc
    int K, int lda, int ldb, int ldc,
    size_t sAz, size_t sBz, size_t sCz,
    int nBlk, int mPerXcd, int swapBig)
{
    __shared__ unsigned short sm[65536];    // 128 KiB: [A|B][buf][half][128][64]

    const int id = blockIdx.x;
    const int xcd = id & 7;
    int s = id >> 3;
    const int perXcd = mPerXcd * nBlk;
    const int z = s / perXcd;
    s -= z * perXcd;
    const int bigB   = xcd * mPerXcd + s / nBlk;
    const int smallB = s - (s / nBlk) * nBlk;
    const int mB = swapBig ? smallB : bigB;
    const int nB = swapBig ? bigB : smallB;

    const unsigned short* Ab = A + (size_t)z * sAz;
    const unsigned short* Bb = BT + (size_t)z * sBz;

    const int tid  = threadIdx.x;
    const int wv   = tid >> 6;
    const int lane = tid & 63;
    const int quad = lane >> 4;
    const int l16  = lane & 15;
    const int wm   = wv >> 2;               // 0..1
    const int wn   = wv & 3;                // 0..3

    const size_t bm = (size_t)mB * 256;
    const size_t bn = (size_t)nB * 256;

    // staging source (per thread): within-half row r0 = tid>>3, logical 16B
    // slot slog = phys_slot ^ (row&7)  (phys slot = tid&7, row&7 == r0&7)
    const int r0   = tid >> 3;
    const int slog = (tid & 7) ^ (r0 & 7);
    const unsigned short* aP = Ab + (bm + r0) * (size_t)lda + slog * 8;
    const unsigned short* bP = Bb + (bn + r0) * (size_t)ldb + slog * 8;

    // stage dest (shorts, within half): wave-uniform base wv*512; j=1: +4096
    const int stA = wv * 512;

    // ds_read offsets (shorts): phys slot = (ks*4+quad) ^ (l16&7);
    // ks=1 slot = ks=0 slot ^ 4  ->  "^ 32" on the short offset.
    const int soff0 = (quad ^ (l16 & 7)) * 8;
    const int arow0 = (wm * 64 + l16) * 64 + soff0;
    const int brow0 = (wn * 32 + l16) * 64 + soff0;

    v4f  acc[8][4] = {};
    v8bf aF[4][2];          // A frags of current quadrant's M-half
    v8bf b1[2][2];          // B(nh1) of current tile
    v8bf b0a[2][2];         // B(nh0), even tiles
    v8bf b0b[2][2];         // B(nh0), odd tiles

    const int NT = K >> 6;  // even, >= 2

    // ---- prologue: stage tile0 {A0,A1,B0,B1} + tile1 {A0,B0,B1};
    //      then early-read B0(tile0) into b0a ----
    {
        gload_lds16(aP,                sm + stA);
        gload_lds16(aP + 64 * lda,     sm + stA + 4096);
        gload_lds16(aP + 128 * lda,    sm + 8192 + stA);
        gload_lds16(aP + 192 * lda,    sm + 8192 + stA + 4096);
        gload_lds16(bP,                sm + 32768 + stA);
        gload_lds16(bP + 64 * ldb,     sm + 32768 + stA + 4096);
        gload_lds16(bP + 128 * ldb,    sm + 32768 + 8192 + stA);
        gload_lds16(bP + 192 * ldb,    sm + 32768 + 8192 + stA + 4096);
        gload_lds16(aP + 64,                 sm + 16384 + stA);
        gload_lds16(aP + 64 * lda + 64,      sm + 16384 + stA + 4096);
        gload_lds16(bP + 64,                 sm + 32768 + 16384 + stA);
        gload_lds16(bP + 64 * ldb + 64,      sm + 32768 + 16384 + stA + 4096);
        gload_lds16(bP + 128 * ldb + 64,     sm + 32768 + 16384 + 8192 + stA);
        gload_lds16(bP + 192 * ldb + 64,     sm + 32768 + 16384 + 8192 + stA + 4096);
        asm volatile("s_waitcnt vmcnt(6)" ::: "memory");   // tile0 landed
        __builtin_amdgcn_s_barrier();
        #pragma unroll
        for (int ni = 0; ni < 2; ++ni) {   // B0(tile0); drained by ph1 lgkm0
            b0a[ni][0] = *(const v8bf*)(sm + 32768 + (brow0 + ni * 1024));
            b0a[ni][1] = *(const v8bf*)(sm + 32768 + ((brow0 + ni * 1024) ^ 32));
        }
        asm volatile("" ::: "memory");
    }

    for (int it = 0; it < (NT >> 1); ++it) {
        const int t0 = it * 2;
        GTILE(t0,     0, b0a, b0b);
        GTILE(t0 + 1, 1, b0b, b0a);
    }

    // ---- epilogue ----
    if (WRITE_BF16) {
        unsigned short* Cb = (unsigned short*)C + (size_t)z * sCz;
        #pragma unroll
        for (int mh = 0; mh < 2; ++mh)
            #pragma unroll
            for (int mi = 0; mi < 4; ++mi) {
                const size_t row0 = bm + mh * 128 + wm * 64 + mi * 16 + quad * 4;
                #pragma unroll
                for (int nh = 0; nh < 2; ++nh)
                    #pragma unroll
                    for (int ni = 0; ni < 2; ++ni) {
                        const size_t col = bn + nh * 128 + wn * 32 + ni * 16 + l16;
                        #pragma unroll
                        for (int r = 0; r < 4; ++r)
                            Cb[(row0 + r) * (size_t)ldc + col] =
                                f2bf(acc[mh * 4 + mi][nh * 2 + ni][r]);
                    }
            }
    } else {
        float* Cb = (float*)C + (size_t)z * sCz;
        #pragma unroll
        for (int mh = 0; mh < 2; ++mh)
            #pragma unroll
            for (int mi = 0; mi < 4; ++mi) {
                const size_t row0 = bm + mh * 128 + wm * 64 + mi * 16 + quad * 4;
                #pragma unroll
                for (int nh = 0; nh < 2; ++nh)
                    #pragma unroll
                    for (int ni = 0; ni < 2; ++ni) {
                        const size_t col = bn + nh * 128 + wn * 32 + ni * 16 + l16;
                        #pragma unroll
                        for (int r = 0; r < 4; ++r)
                            Cb[(row0 + r) * (size_t)ldc + col] =
                                acc[mh * 4 + mi][nh * 2 + ni][r];
                    }
            }
    }
}
#undef GTILE
#undef MFMA_Q

// ---------------------------------------------------------------------------
// Gram via MFMA from CHANNEL-MAJOR qkT: no LDS transpose at all.
// partial[split][bh][c][d] = sum_{n in split} qkT[c][n]*qkT[d][n].
// Per block: stage [64 ch][512 tok] = 64 KiB via global_load_lds (linear dest,
// inverse-swizzled source), then 16 K-steps of 32 with swizzled ds_read_b128.
// 512 blocks = exactly 2 blocks/CU (128 KiB LDS).
// ---------------------------------------------------------------------------
__global__ __launch_bounds__(256, 2) void gram_kernel(
    const unsigned short* __restrict__ qkT,  // [1024 ch][16384 tok] bf16
    float* __restrict__ partial)             // [16][32][64][64]
{
    const int bh = blockIdx.x;               // b*16+h
    const int split = blockIdx.y;            // 0..15
    const int b = bh >> 4, h = bh & 15;
    const unsigned short* base =
        qkT + (size_t)(h * 64) * 16384 + (size_t)b * 8192 + (size_t)split * 512;

    __shared__ unsigned short sM[64 * 512];  // [ch][tok'], 64 KiB, slot-swizzled
    const int tid = threadIdx.x;
    const int wv = tid >> 6, lane = tid & 63, quad = lane >> 4, l16 = lane & 15;

    // stage: issue i covers rows i*4 + wv; lane deposits at phys slot = lane.
    #pragma unroll
    for (int i = 0; i < 16; i++) {
        const int row = i * 4 + wv;
        const int lo  = (lane & 56) | ((lane & 7) ^ (row & 7));
        gload_lds16(base + (size_t)row * 16384 + lo * 8,
                    sM + (size_t)i * 2048 + wv * 512);
    }
    __syncthreads();   // compiler drains vmcnt before the barrier

    v4f acc[4] = {};
    const int cha = 16 * wv + l16;

    #pragma unroll
    for (int ks = 0; ks < 16; ks++) {
        const int lg = ks * 4 + quad;                       // logical 16B chunk
        const int so = ((lg & 56) | ((lg & 7) ^ (l16 & 7))) * 8;  // shorts
        const v8bf a = *(const v8bf*)&sM[(size_t)cha * 512 + so];
        #pragma unroll
        for (int t = 0; t < 4; t++) {
            const v8bf bb = *(const v8bf*)&sM[(size_t)(t * 16 + l16) * 512 + so];
            acc[t] = __builtin_amdgcn_mfma_f32_16x16x32_bf16(a, bb, acc[t], 0, 0, 0);
        }
    }

    float* outp = partial + ((size_t)split * 32 + bh) * 4096;
    #pragma unroll
    for (int t = 0; t < 4; t++)
        #pragma unroll
        for (int r = 0; r < 4; r++)
            outp[(size_t)(16 * wv + quad * 4 + r) * 64 + t * 16 + l16] = acc[t][r];
}

// ---------------------------------------------------------------------------
// Softmax: one wave per (bh, c) row over d (64 lanes). Writes TRANSPOSED
// attnT[bh][d][c] so wefft can load without an LDS transpose.
// ---------------------------------------------------------------------------
__global__ __launch_bounds__(256) void softmax_kernel(
    const float* __restrict__ partial,   // [16][32][4096]
    const float* __restrict__ tau,       // [16]
    float* __restrict__ attnT)           // [32][64(d)][64(c)]
{
    const int gw = (int)((blockIdx.x * 256 + threadIdx.x) >> 6);  // 0..2047
    const int d = threadIdx.x & 63;
    const int bh = gw >> 6;
    const int c = gw & 63;
    const int h = bh & 15;

    float cd = 0.f, cc = 0.f, dd = 0.f;
    #pragma unroll
    for (int s = 0; s < 16; s++) {
        const float* p = partial + ((size_t)s * 32 + bh) * 4096;
        cd += p[c * 64 + d];
        cc += p[c * 65];
        dd += p[d * 65];
    }
    const float INV_SQRT_N = 0.011048543456039806f;  // 1/sqrt(8192)
    const float logit = (2.f * cd - cc - dd) * INV_SQRT_N * tau[h];

    float m = logit;
    #pragma unroll
    for (int off = 32; off > 0; off >>= 1) m = fmaxf(m, __shfl_xor(m, off, 64));
    const float e = __expf(logit - m);
    float sum = e;
    #pragma unroll
    for (int off = 32; off > 0; off >>= 1) sum += __shfl_xor(sum, off, 64);

    attnT[(size_t)bh * 4096 + d * 64 + c] = e / sum;
}

// ---------------------------------------------------------------------------
// WeffT[b][j][h*64+d] = sum_c attn[b,h,c,d] * W_out[h*64+c, j]   (bf16 out)
// ---------------------------------------------------------------------------
__global__ __launch_bounds__(256) void wefft_kernel(
    const float* __restrict__ attnT,      // [32][64(d)][64(c)]
    const float* __restrict__ Wout,       // [1024][1024] fp32
    unsigned short* __restrict__ weffT)   // [2][1024][1024] bf16 (j, i)
{
    const int bh = blockIdx.x;            // 0..31
    const int jg = blockIdx.y;            // 0..15
    const int b = bh >> 4, h = bh & 15;

    __shared__ float sAttT[64][65];       // [d][c]
    __shared__ float sW[64][65];          // [c][j_local]
    const int tid = threadIdx.x;
    const float* ap = attnT + (size_t)bh * 4096;
    const float* wp = Wout + (size_t)(h * 64) * 1024 + jg * 64;
    for (int i = tid; i < 4096; i += 256) {
        const int r = i >> 6, q = i & 63;
        sAttT[r][q] = ap[i];              // already transposed in global
        sW[r][q] = wp[(size_t)r * 1024 + q];
    }
    __syncthreads();

    const int dd0 = (tid >> 4) << 2;
    const int j0  = (tid & 15) << 2;
    float acc[4][4] = {};
    for (int cc = 0; cc < 64; cc++) {
        float av[4], wvv[4];
        #pragma unroll
        for (int i = 0; i < 4; i++) av[i] = sAttT[dd0 + i][cc];
        #pragma unroll
        for (int i = 0; i < 4; i++) wvv[i] = sW[cc][j0 + i];
        #pragma unroll
        for (int i = 0; i < 4; i++)
            #pragma unroll
            for (int j = 0; j < 4; j++)
                acc[i][j] += av[i] * wvv[j];
    }

    unsigned short* op = weffT + ((size_t)b * 1024 + jg * 64) * 1024 + h * 64;
    #pragma unroll
    for (int i = 0; i < 4; i++)
        #pragma unroll
        for (int j = 0; j < 4; j++)
            op[(size_t)(j0 + j) * 1024 + dd0 + i] = f2bf(acc[i][j]);
}

// ---------------------------------------------------------------------------
// Fused conversions: x -> bf16 (16384 blks), Wv -> bf16 (1024 blks),
// Wqk -> transposed bf16 (1024 tile blks). One dispatch.
// ---------------------------------------------------------------------------
__global__ __launch_bounds__(256) void cvt_all_kernel(
    const float* __restrict__ x, const float* __restrict__ Wv,
    const float* __restrict__ Wqk,
    unsigned short* __restrict__ xb, unsigned short* __restrict__ wvb,
    unsigned short* __restrict__ wqkT)
{
    const int bid = blockIdx.x;
    if (bid < 17408) {
        const float* src = (bid < 16384) ? x : Wv;
        unsigned short* dst = (bid < 16384) ? xb : wvb;
        const size_t blk = (bid < 16384) ? bid : (bid - 16384);
        const size_t i = (blk * 256 + threadIdx.x) * 4;
        const float4 v = *(const float4*)(src + i);
        ushort4 o;
        o.x = f2bf(v.x); o.y = f2bf(v.y); o.z = f2bf(v.z); o.w = f2bf(v.w);
        *(ushort4*)(dst + i) = o;
    } else {
        const int t = bid - 17408;
        const int n0 = (t & 31) * 32, k0 = (t >> 5) * 32;
        __shared__ float sT[32][33];
        const int tx = threadIdx.x & 31, ty = threadIdx.x >> 5;
        #pragma unroll
        for (int i = ty; i < 32; i += 8)
            sT[i][tx] = Wqk[(size_t)(k0 + i) * 1024 + n0 + tx];
        __syncthreads();
        #pragma unroll
        for (int i = ty; i < 32; i += 8)
            wqkT[(size_t)(n0 + i) * 1024 + k0 + tx] = f2bf(sT[tx][i]);
    }
}

// ---------------------------------------------------------------------------
extern "C" void kernel_launch(void* const* d_in, const int* in_sizes, int n_in,
                              void* d_out, int out_size, void* d_ws, size_t ws_size,
                              hipStream_t stream)
{
    (void)in_sizes; (void)n_in; (void)out_size; (void)ws_size;
    const float* x    = (const float*)d_in[0];
    const float* Wqk  = (const float*)d_in[1];
    const float* Wv   = (const float*)d_in[2];
    const float* Wout = (const float*)d_in[3];
    const float* tau  = (const float*)d_in[4];

    // out_b = x_b @ (W_v @ Weff_b); v never materialized.
    // qk is computed TRANSPOSED (qkT = Wqk^T @ x^T, channel-major) so gram
    // needs no LDS transpose.
    // ws layout:
    //   xb     : 16384x1024  bf16 (32 MB)
    //   wqkT   : 1024x1024   bf16 ( 2 MB)
    //   wvb    : 1024x1024   bf16 ( 2 MB)
    //   qkT    : 1024x16384  bf16 (32 MB)
    //   partial: 16x32x4096  f32  ( 8 MB)
    //   attnT  : 32x4096     f32  (.5 MB)
    //   weffT  : 2x1024x1024 bf16 ( 4 MB)
    //   wfoldT : 2x1024x1024 bf16 ( 4 MB)
    unsigned short* xb     = (unsigned short*)d_ws;
    unsigned short* wqkT   = xb + (size_t)16384 * 1024;
    unsigned short* wvb    = wqkT + (size_t)1024 * 1024;
    unsigned short* qkT    = wvb + (size_t)1024 * 1024;
    float*          partial= (float*)(qkT + (size_t)16384 * 1024);
    float*          attnT  = partial + (size_t)16 * 32 * 4096;
    unsigned short* weffT  = (unsigned short*)(attnT + (size_t)32 * 4096);
    unsigned short* wfoldT = weffT + (size_t)2 * 1024 * 1024;

    cvt_all_kernel<<<18432, 256, 0, stream>>>(x, Wv, Wqk, xb, wvb, wqkT);

    // qkT = Wqk^T @ x^T: C[c][n], M=1024 (4 m-blks), N=16384 (64 n-blks).
    // swapBig=1: each XCD owns 8 contiguous n-blocks (token range); the 4
    // m-blocks per n-strip are adjacent in dispatch order (share B strip).
    gemm256_bt<1><<<256, 512, 0, stream>>>(
        wqkT, xb, (void*)qkT, 1024, 1024, 1024, 16384, 0, 0, 0, 4, 8, 1);

    gram_kernel<<<dim3(32, 16), 256, 0, stream>>>(qkT, partial);
    softmax_kernel<<<512, 256, 0, stream>>>(partial, tau, attnT);
    wefft_kernel<<<dim3(32, 16), 256, 0, stream>>>(attnT, Wout, weffT);

    // WfoldT_b[j][c'] = sum_i WeffT_b[j][i] * W_v[c'][i]: small, keep 128^2
    gemm_bt<1><<<128, 256, 0, stream>>>(
        weffT, wvb, (void*)wfoldT, 1024, 1024, 1024, 1024,
        (size_t)1024 * 1024, 0, (size_t)1024 * 1024, 8, 1);

    // out_b = x_b @ Wfold_b  (M=8192/z, N=1024, K=1024): 32 m x 4 n x 2 z = 256
    gemm256_bt<0><<<256, 512, 0, stream>>>(
        xb, wfoldT, d_out, 1024, 1024, 1024, 1024,
        (size_t)8192 * 1024, (size_t)1024 * 1024, (size_t)8192 * 1024, 4, 4, 0);
}

// Round 6
// 254.875 us; speedup vs baseline: 1.0291x; 1.0291x over previous
//
#include <hip/hip_runtime.h>
#include <hip/hip_bf16.h>
#include <cstdint>
#include <cstddef>

// MFMA fragment types (gfx950: V8y operands, V4f accumulator)
typedef __bf16 v8bf __attribute__((ext_vector_type(8)));
typedef float  v4f  __attribute__((ext_vector_type(4)));

__device__ __forceinline__ unsigned short f2bf(float f) {
    unsigned int u = __float_as_uint(f);
    u += 0x7fffu + ((u >> 16) & 1u);   // round-to-nearest-even
    return (unsigned short)(u >> 16);
}

// async global->LDS, 16B per lane. LDS deposit is wave-uniform base + lane*16;
// the GLOBAL source address is per-lane.
__device__ __forceinline__ void gload_lds16(const unsigned short* g, unsigned short* l) {
    __builtin_amdgcn_global_load_lds(
        (const __attribute__((address_space(1))) unsigned int*)(uintptr_t)g,
        (__attribute__((address_space(3))) unsigned int*)(uintptr_t)l, 16, 0, 0);
}

// ---------------------------------------------------------------------------
// Legacy 128x128 GEMM (kept only for the small Wfold GEMM, 128 blocks).
// C[M,N] = A[M,K] * B[K,N], B transposed (BT is N x K). bf16 in, fp32 acc.
// ---------------------------------------------------------------------------
template<int WRITE_BF16>
__global__ __launch_bounds__(256, 2) void gemm_bt(
    const unsigned short* __restrict__ A,   // M x K, row stride lda (bf16)
    const unsigned short* __restrict__ BT,  // N x K, row stride ldb (bf16)
    void* __restrict__ C,                   // M x N, row stride ldc
    int K, int lda, int ldb, int ldc,
    size_t sAz, size_t sBz, size_t sCz,     // per-z strides (elements)
    int nBlk, int mPerXcd)
{
    __shared__ unsigned short sA[128 * 32];
    __shared__ unsigned short sB[128 * 32];

    const int id = blockIdx.x;
    const int xcd = id & 7;
    int s = id >> 3;
    const int perXcd = mPerXcd * nBlk;
    const int z = s / perXcd;
    s -= z * perXcd;
    const int mB = xcd * mPerXcd + s / nBlk;
    const int nB = s - (s / nBlk) * nBlk;

    const unsigned short* Ab = A + (size_t)z * sAz;
    const unsigned short* Bb = BT + (size_t)z * sBz;

    const int tid  = threadIdx.x;
    const int wv   = tid >> 6;
    const int lane = tid & 63;
    const int quad = lane >> 4;
    const int l16  = lane & 15;
    const size_t bm = (size_t)mB * 128;
    const size_t bn = (size_t)nB * 128;
    const int wm = (wv >> 1) * 64;
    const int wn = (wv & 1) * 64;

    const int ro = tid >> 2;
    const int ko = (((tid & 3) ^ (ro & 3)) << 3);

    const unsigned short* aptr0 = Ab + (bm + ro)      * (size_t)lda + ko;
    const unsigned short* aptr1 = Ab + (bm + ro + 64) * (size_t)lda + ko;
    const unsigned short* bptr0 = Bb + (bn + ro)      * (size_t)ldb + ko;
    const unsigned short* bptr1 = Bb + (bn + ro + 64) * (size_t)ldb + ko;

    unsigned short* sA0 = &sA[wv * 512];
    unsigned short* sA1 = &sA[2048 + wv * 512];
    unsigned short* sB0 = &sB[wv * 512];
    unsigned short* sB1 = &sB[2048 + wv * 512];

    const int sslot = ((quad ^ (l16 & 3)) << 3);

    v4f acc[4][4] = {};

    for (int k0 = 0; k0 < K; k0 += 32) {
        gload_lds16(aptr0 + k0, sA0);
        gload_lds16(aptr1 + k0, sA1);
        gload_lds16(bptr0 + k0, sB0);
        gload_lds16(bptr1 + k0, sB1);
        __syncthreads();

        v8bf af[4], bfr[4];
        #pragma unroll
        for (int t = 0; t < 4; t++) {
            af[t]  = *(const v8bf*)&sA[(size_t)(wm + t * 16 + l16) * 32 + sslot];
            bfr[t] = *(const v8bf*)&sB[(size_t)(wn + t * 16 + l16) * 32 + sslot];
        }

        #pragma unroll
        for (int ti = 0; ti < 4; ti++)
            #pragma unroll
            for (int tj = 0; tj < 4; tj++)
                acc[ti][tj] = __builtin_amdgcn_mfma_f32_16x16x32_bf16(
                    af[ti], bfr[tj], acc[ti][tj], 0, 0, 0);
        __syncthreads();
    }

    if (WRITE_BF16) {
        unsigned short* Cb = (unsigned short*)C + (size_t)z * sCz;
        #pragma unroll
        for (int ti = 0; ti < 4; ti++) {
            const size_t row0 = bm + wm + ti * 16 + quad * 4;
            #pragma unroll
            for (int tj = 0; tj < 4; tj++) {
                const size_t col = bn + wn + tj * 16 + l16;
                #pragma unroll
                for (int r = 0; r < 4; r++)
                    Cb[(row0 + r) * (size_t)ldc + col] = f2bf(acc[ti][tj][r]);
            }
        }
    } else {
        float* Cb = (float*)C + (size_t)z * sCz;
        #pragma unroll
        for (int ti = 0; ti < 4; ti++) {
            const size_t row0 = bm + wm + ti * 16 + quad * 4;
            #pragma unroll
            for (int tj = 0; tj < 4; tj++) {
                const size_t col = bn + wn + tj * 16 + l16;
                #pragma unroll
                for (int r = 0; r < 4; r++)
                    Cb[(row0 + r) * (size_t)ldc + col] = acc[ti][tj][r];
            }
        }
    }
}

// ---------------------------------------------------------------------------
// 256x256-tile, BK=64, 8-wave (2Mx4N) GEMM with counted vmcnt.
// ROUND-6: TWO phases per K-tile (4 barriers) instead of four (8 barriers).
// Cycle model: MFMA 2480 + LDS-rd 750 (256B/cyc) + stage-wr 250 = 3500 cyc
// per K-tile vs 6630 measured at 4 phases -> ~3100 cyc in 8 barrier drains.
// Halving barriers targets that term.  History: r1 4-phase 44.2us (prev
// best); r2/r4/r5 read-placement tweaks all regressed (49-51us).
// Phase map per K-tile t (p = t&1, steady state):
//  phA: rd A(mh0)x8 + B(nh0)x4 + B(nh1)x4 ; stage A1(t+1)->buf p^1 ;
//       vmcnt(8) ; bar ; lgkm0 ; MFMA(0,0)[b0] MFMA(0,1)[b1] ; bar
//  phB: rd A(mh1)x8                       ; stage A0,B0,B1(t+2)->buf p ;
//       vmcnt(8) ; bar ; lgkm0 ; MFMA(1,1)[b1] MFMA(1,0)[b0] ; bar
// vmcnt audit (steady state, 2 issues phA / 6 issues phB):
//  phA wait: in-flight 10 = [A1(t):2, A0B0B1(t+1):6, A1(t+1):2] -> vmcnt(8)
//            drains A1(t), needed by THIS tile's phB reads.
//  phB wait: in-flight 14 = [A0B0B1(t+1):6, A1(t+1):2, A0B0B1(t+2):6]
//            -> vmcnt(8) drains A0B0B1(t+1), needed by NEXT tile's phA.
//  Tail: phA no-stage -> vmcnt(0); phB no-stage -> vmcnt(2).
// Overwrite-safety: phA stages A1->buf p^1 (last read: phB(t-1), behind its
// closing barrier); phB stages A0/B0/B1->buf p (last read: phA(t), behind
// its closing barrier).  NT >= 2.
// ---------------------------------------------------------------------------
#define MFMA_Q(MH, NH, BF)                                                    \
    do {                                                                      \
        __builtin_amdgcn_s_setprio(1);                                        \
        _Pragma("unroll")                                                     \
        for (int mi = 0; mi < 4; ++mi) {                                      \
            _Pragma("unroll")                                                 \
            for (int ni = 0; ni < 2; ++ni) {                                  \
                acc[(MH)*4 + mi][(NH)*2 + ni] =                               \
                    __builtin_amdgcn_mfma_f32_16x16x32_bf16(                  \
                        aF[mi][0], BF[ni][0],                                 \
                        acc[(MH)*4 + mi][(NH)*2 + ni], 0, 0, 0);              \
                acc[(MH)*4 + mi][(NH)*2 + ni] =                               \
                    __builtin_amdgcn_mfma_f32_16x16x32_bf16(                  \
                        aF[mi][1], BF[ni][1],                                 \
                        acc[(MH)*4 + mi][(NH)*2 + ni], 0, 0, 0);              \
            }                                                                 \
        }                                                                     \
        __builtin_amdgcn_s_setprio(0);                                        \
    } while (0)

template<int WRITE_BF16>
__global__ __launch_bounds__(512, 2) void gemm256_bt(
    const unsigned short* __restrict__ A,   // M x K (bf16), row stride lda
    const unsigned short* __restrict__ BT,  // N x K (bf16), row stride ldb
    void* __restrict__ C,                   // M x N, row stride ldc
    int K, int lda, int ldb, int ldc,
    size_t sAz, size_t sBz, size_t sCz,
    int nBlk, int mPerXcd, int swapBig)
{
    __shared__ unsigned short sm[65536];    // 128 KiB: [A|B][buf][half][128][64]

    const int id = blockIdx.x;
    const int xcd = id & 7;
    int s = id >> 3;
    const int perXcd = mPerXcd * nBlk;
    const int z = s / perXcd;
    s -= z * perXcd;
    const int bigB   = xcd * mPerXcd + s / nBlk;
    const int smallB = s - (s / nBlk) * nBlk;
    const int mB = swapBig ? smallB : bigB;
    const int nB = swapBig ? bigB : smallB;

    const unsigned short* Ab = A + (size_t)z * sAz;
    const unsigned short* Bb = BT + (size_t)z * sBz;

    const int tid  = threadIdx.x;
    const int wv   = tid >> 6;
    const int lane = tid & 63;
    const int quad = lane >> 4;
    const int l16  = lane & 15;
    const int wm   = wv >> 2;               // 0..1
    const int wn   = wv & 3;                // 0..3

    const size_t bm = (size_t)mB * 256;
    const size_t bn = (size_t)nB * 256;

    // staging source (per thread): within-half row r0 = tid>>3, logical 16B
    // slot slog = phys_slot ^ (row&7)  (phys slot = tid&7, row&7 == r0&7)
    const int r0   = tid >> 3;
    const int slog = (tid & 7) ^ (r0 & 7);
    const unsigned short* aP = Ab + (bm + r0) * (size_t)lda + slog * 8;
    const unsigned short* bP = Bb + (bn + r0) * (size_t)ldb + slog * 8;

    // stage dest (shorts, within half): wave-uniform base wv*512; j=1: +4096
    const int stA = wv * 512;

    // ds_read offsets (shorts): phys slot = (ks*4+quad) ^ (l16&7);
    // ks=1 slot = ks=0 slot ^ 4  ->  "^ 32" on the short offset.
    const int soff0 = (quad ^ (l16 & 7)) * 8;
    const int arow0 = (wm * 64 + l16) * 64 + soff0;
    const int brow0 = (wn * 32 + l16) * 64 + soff0;

    v4f  acc[8][4] = {};
    v8bf aF[4][2];          // A frags of current quadrant's M-half
    v8bf b0[2][2];          // B(nh0) of current tile (live phA->phB)
    v8bf b1[2][2];          // B(nh1) of current tile (live phA->phB)

    const int NT = K >> 6;  // >= 2

    // ---- prologue: issue order fixes drain order:
    //      A0B0B1(0) [oldest 6] ; A1(0) ; A0B0B1(1) ; then vmcnt(8) ----
    {
        gload_lds16(aP,                sm + stA);
        gload_lds16(aP + 64 * lda,     sm + stA + 4096);
        gload_lds16(bP,                sm + 32768 + stA);
        gload_lds16(bP + 64 * ldb,     sm + 32768 + stA + 4096);
        gload_lds16(bP + 128 * ldb,    sm + 32768 + 8192 + stA);
        gload_lds16(bP + 192 * ldb,    sm + 32768 + 8192 + stA + 4096);
        gload_lds16(aP + 128 * lda,    sm + 8192 + stA);
        gload_lds16(aP + 192 * lda,    sm + 8192 + stA + 4096);
        if (NT > 1) {
            gload_lds16(aP + 64,                 sm + 16384 + stA);
            gload_lds16(aP + 64 * lda + 64,      sm + 16384 + stA + 4096);
            gload_lds16(bP + 64,                 sm + 32768 + 16384 + stA);
            gload_lds16(bP + 64 * ldb + 64,      sm + 32768 + 16384 + stA + 4096);
            gload_lds16(bP + 128 * ldb + 64,     sm + 32768 + 16384 + 8192 + stA);
            gload_lds16(bP + 192 * ldb + 64,     sm + 32768 + 16384 + 8192 + stA + 4096);
            asm volatile("s_waitcnt vmcnt(8)" ::: "memory");   // A0B0B1(0) landed
        } else {
            asm volatile("s_waitcnt vmcnt(0)" ::: "memory");
        }
        __builtin_amdgcn_s_barrier();
    }

    for (int t = 0; t < NT; ++t) {
        const int p = t & 1;
        const unsigned short* sa = sm + p * 16384;
        const unsigned short* sb = sm + 32768 + p * 16384;
        unsigned short* dq = sm + (p ^ 1) * 16384;    // buf of tile t+1
        unsigned short* dp = sm + p * 16384;          // buf of tile t+2
        const int kk1 = (t + 1) * 64;
        const int kk2 = (t + 2) * 64;

        // ---- phase A: rd A(mh0) + B(nh0) + B(nh1); stage A1(t+1) ----
        #pragma unroll
        for (int mi = 0; mi < 4; ++mi) {
            aF[mi][0] = *(const v8bf*)(sa + (arow0 + mi * 1024));
            aF[mi][1] = *(const v8bf*)(sa + ((arow0 + mi * 1024) ^ 32));
        }
        #pragma unroll
        for (int ni = 0; ni < 2; ++ni) {
            b0[ni][0] = *(const v8bf*)(sb + (brow0 + ni * 1024));
            b0[ni][1] = *(const v8bf*)(sb + ((brow0 + ni * 1024) ^ 32));
            b1[ni][0] = *(const v8bf*)(sb + 8192 + (brow0 + ni * 1024));
            b1[ni][1] = *(const v8bf*)(sb + 8192 + ((brow0 + ni * 1024) ^ 32));
        }
        if (t + 1 < NT) {
            gload_lds16(aP + 128 * lda + kk1, dq + 8192 + stA);
            gload_lds16(aP + 192 * lda + kk1, dq + 8192 + stA + 4096);
            asm volatile("s_waitcnt vmcnt(8)" ::: "memory");   // drains A1(t)
        } else {
            asm volatile("s_waitcnt vmcnt(0)" ::: "memory");
        }
        __builtin_amdgcn_s_barrier();
        asm volatile("s_waitcnt lgkmcnt(0)" ::: "memory");
        MFMA_Q(0, 0, b0);
        MFMA_Q(0, 1, b1);
        __builtin_amdgcn_s_barrier();

        // ---- phase B: rd A(mh1); stage A0,B0,B1(t+2) ----
        #pragma unroll
        for (int mi = 0; mi < 4; ++mi) {
            aF[mi][0] = *(const v8bf*)(sa + 8192 + (arow0 + mi * 1024));
            aF[mi][1] = *(const v8bf*)(sa + 8192 + ((arow0 + mi * 1024) ^ 32));
        }
        if (t + 2 < NT) {
            gload_lds16(aP + kk2,             dp + stA);
            gload_lds16(aP + 64 * lda + kk2,  dp + stA + 4096);
            gload_lds16(bP + kk2,             dp + 32768 + stA);
            gload_lds16(bP + 64 * ldb + kk2,  dp + 32768 + stA + 4096);
            gload_lds16(bP + 128 * ldb + kk2, dp + 32768 + 8192 + stA);
            gload_lds16(bP + 192 * ldb + kk2, dp + 32768 + 8192 + stA + 4096);
            asm volatile("s_waitcnt vmcnt(8)" ::: "memory");   // drains A0B0B1(t+1)
        } else {
            asm volatile("s_waitcnt vmcnt(2)" ::: "memory");
        }
        __builtin_amdgcn_s_barrier();
        asm volatile("s_waitcnt lgkmcnt(0)" ::: "memory");
        MFMA_Q(1, 1, b1);
        MFMA_Q(1, 0, b0);
        __builtin_amdgcn_s_barrier();
    }

    // ---- epilogue ----
    if (WRITE_BF16) {
        unsigned short* Cb = (unsigned short*)C + (size_t)z * sCz;
        #pragma unroll
        for (int mh = 0; mh < 2; ++mh)
            #pragma unroll
            for (int mi = 0; mi < 4; ++mi) {
                const size_t row0 = bm + mh * 128 + wm * 64 + mi * 16 + quad * 4;
                #pragma unroll
                for (int nh = 0; nh < 2; ++nh)
                    #pragma unroll
                    for (int ni = 0; ni < 2; ++ni) {
                        const size_t col = bn + nh * 128 + wn * 32 + ni * 16 + l16;
                        #pragma unroll
                        for (int r = 0; r < 4; ++r)
                            Cb[(row0 + r) * (size_t)ldc + col] =
                                f2bf(acc[mh * 4 + mi][nh * 2 + ni][r]);
                    }
            }
    } else {
        float* Cb = (float*)C + (size_t)z * sCz;
        #pragma unroll
        for (int mh = 0; mh < 2; ++mh)
            #pragma unroll
            for (int mi = 0; mi < 4; ++mi) {
                const size_t row0 = bm + mh * 128 + wm * 64 + mi * 16 + quad * 4;
                #pragma unroll
                for (int nh = 0; nh < 2; ++nh)
                    #pragma unroll
                    for (int ni = 0; ni < 2; ++ni) {
                        const size_t col = bn + nh * 128 + wn * 32 + ni * 16 + l16;
                        #pragma unroll
                        for (int r = 0; r < 4; ++r)
                            Cb[(row0 + r) * (size_t)ldc + col] =
                                acc[mh * 4 + mi][nh * 2 + ni][r];
                    }
            }
    }
}
#undef MFMA_Q

// ---------------------------------------------------------------------------
// Gram via MFMA from CHANNEL-MAJOR qkT: no LDS transpose at all.
// partial[split][bh][c][d] = sum_{n in split} qkT[c][n]*qkT[d][n].
// Per block: stage [64 ch][512 tok] = 64 KiB via global_load_lds (linear dest,
// inverse-swizzled source), then 16 K-steps of 32 with swizzled ds_read_b128.
// 512 blocks = exactly 2 blocks/CU (128 KiB LDS).
// ---------------------------------------------------------------------------
__global__ __launch_bounds__(256, 2) void gram_kernel(
    const unsigned short* __restrict__ qkT,  // [1024 ch][16384 tok] bf16
    float* __restrict__ partial)             // [16][32][64][64]
{
    const int bh = blockIdx.x;               // b*16+h
    const int split = blockIdx.y;            // 0..15
    const int b = bh >> 4, h = bh & 15;
    const unsigned short* base =
        qkT + (size_t)(h * 64) * 16384 + (size_t)b * 8192 + (size_t)split * 512;

    __shared__ unsigned short sM[64 * 512];  // [ch][tok'], 64 KiB, slot-swizzled
    const int tid = threadIdx.x;
    const int wv = tid >> 6, lane = tid & 63, quad = lane >> 4, l16 = lane & 15;

    // stage: issue i covers rows i*4 + wv; lane deposits at phys slot = lane.
    #pragma unroll
    for (int i = 0; i < 16; i++) {
        const int row = i * 4 + wv;
        const int lo  = (lane & 56) | ((lane & 7) ^ (row & 7));
        gload_lds16(base + (size_t)row * 16384 + lo * 8,
                    sM + (size_t)i * 2048 + wv * 512);
    }
    __syncthreads();   // compiler drains vmcnt before the barrier

    v4f acc[4] = {};
    const int cha = 16 * wv + l16;

    #pragma unroll
    for (int ks = 0; ks < 16; ks++) {
        const int lg = ks * 4 + quad;                       // logical 16B chunk
        const int so = ((lg & 56) | ((lg & 7) ^ (l16 & 7))) * 8;  // shorts
        const v8bf a = *(const v8bf*)&sM[(size_t)cha * 512 + so];
        #pragma unroll
        for (int t = 0; t < 4; t++) {
            const v8bf bb = *(const v8bf*)&sM[(size_t)(t * 16 + l16) * 512 + so];
            acc[t] = __builtin_amdgcn_mfma_f32_16x16x32_bf16(a, bb, acc[t], 0, 0, 0);
        }
    }

    float* outp = partial + ((size_t)split * 32 + bh) * 4096;
    #pragma unroll
    for (int t = 0; t < 4; t++)
        #pragma unroll
        for (int r = 0; r < 4; r++)
            outp[(size_t)(16 * wv + quad * 4 + r) * 64 + t * 16 + l16] = acc[t][r];
}

// ---------------------------------------------------------------------------
// Softmax: one wave per (bh, c) row over d (64 lanes). Writes TRANSPOSED
// attnT[bh][d][c] so wefft can load without an LDS transpose.
// ---------------------------------------------------------------------------
__global__ __launch_bounds__(256) void softmax_kernel(
    const float* __restrict__ partial,   // [16][32][4096]
    const float* __restrict__ tau,       // [16]
    float* __restrict__ attnT)           // [32][64(d)][64(c)]
{
    const int gw = (int)((blockIdx.x * 256 + threadIdx.x) >> 6);  // 0..2047
    const int d = threadIdx.x & 63;
    const int bh = gw >> 6;
    const int c = gw & 63;
    const int h = bh & 15;

    float cd = 0.f, cc = 0.f, dd = 0.f;
    #pragma unroll
    for (int s = 0; s < 16; s++) {
        const float* p = partial + ((size_t)s * 32 + bh) * 4096;
        cd += p[c * 64 + d];
        cc += p[c * 65];
        dd += p[d * 65];
    }
    const float INV_SQRT_N = 0.011048543456039806f;  // 1/sqrt(8192)
    const float logit = (2.f * cd - cc - dd) * INV_SQRT_N * tau[h];

    float m = logit;
    #pragma unroll
    for (int off = 32; off > 0; off >>= 1) m = fmaxf(m, __shfl_xor(m, off, 64));
    const float e = __expf(logit - m);
    float sum = e;
    #pragma unroll
    for (int off = 32; off > 0; off >>= 1) sum += __shfl_xor(sum, off, 64);

    attnT[(size_t)bh * 4096 + d * 64 + c] = e / sum;
}

// ---------------------------------------------------------------------------
// WeffT[b][j][h*64+d] = sum_c attn[b,h,c,d] * W_out[h*64+c, j]   (bf16 out)
// ---------------------------------------------------------------------------
__global__ __launch_bounds__(256) void wefft_kernel(
    const float* __restrict__ attnT,      // [32][64(d)][64(c)]
    const float* __restrict__ Wout,       // [1024][1024] fp32
    unsigned short* __restrict__ weffT)   // [2][1024][1024] bf16 (j, i)
{
    const int bh = blockIdx.x;            // 0..31
    const int jg = blockIdx.y;            // 0..15
    const int b = bh >> 4, h = bh & 15;

    __shared__ float sAttT[64][65];       // [d][c]
    __shared__ float sW[64][65];          // [c][j_local]
    const int tid = threadIdx.x;
    const float* ap = attnT + (size_t)bh * 4096;
    const float* wp = Wout + (size_t)(h * 64) * 1024 + jg * 64;
    for (int i = tid; i < 4096; i += 256) {
        const int r = i >> 6, q = i & 63;
        sAttT[r][q] = ap[i];              // already transposed in global
        sW[r][q] = wp[(size_t)r * 1024 + q];
    }
    __syncthreads();

    const int dd0 = (tid >> 4) << 2;
    const int j0  = (tid & 15) << 2;
    float acc[4][4] = {};
    for (int cc = 0; cc < 64; cc++) {
        float av[4], wvv[4];
        #pragma unroll
        for (int i = 0; i < 4; i++) av[i] = sAttT[dd0 + i][cc];
        #pragma unroll
        for (int i = 0; i < 4; i++) wvv[i] = sW[cc][j0 + i];
        #pragma unroll
        for (int i = 0; i < 4; i++)
            #pragma unroll
            for (int j = 0; j < 4; j++)
                acc[i][j] += av[i] * wvv[j];
    }

    unsigned short* op = weffT + ((size_t)b * 1024 + jg * 64) * 1024 + h * 64;
    #pragma unroll
    for (int i = 0; i < 4; i++)
        #pragma unroll
        for (int j = 0; j < 4; j++)
            op[(size_t)(j0 + j) * 1024 + dd0 + i] = f2bf(acc[i][j]);
}

// ---------------------------------------------------------------------------
// Fused conversions: x -> bf16 (16384 blks), Wv -> bf16 (1024 blks),
// Wqk -> transposed bf16 (1024 tile blks). One dispatch.
// ---------------------------------------------------------------------------
__global__ __launch_bounds__(256) void cvt_all_kernel(
    const float* __restrict__ x, const float* __restrict__ Wv,
    const float* __restrict__ Wqk,
    unsigned short* __restrict__ xb, unsigned short* __restrict__ wvb,
    unsigned short* __restrict__ wqkT)
{
    const int bid = blockIdx.x;
    if (bid < 17408) {
        const float* src = (bid < 16384) ? x : Wv;
        unsigned short* dst = (bid < 16384) ? xb : wvb;
        const size_t blk = (bid < 16384) ? bid : (bid - 16384);
        const size_t i = (blk * 256 + threadIdx.x) * 4;
        const float4 v = *(const float4*)(src + i);
        ushort4 o;
        o.x = f2bf(v.x); o.y = f2bf(v.y); o.z = f2bf(v.z); o.w = f2bf(v.w);
        *(ushort4*)(dst + i) = o;
    } else {
        const int t = bid - 17408;
        const int n0 = (t & 31) * 32, k0 = (t >> 5) * 32;
        __shared__ float sT[32][33];
        const int tx = threadIdx.x & 31, ty = threadIdx.x >> 5;
        #pragma unroll
        for (int i = ty; i < 32; i += 8)
            sT[i][tx] = Wqk[(size_t)(k0 + i) * 1024 + n0 + tx];
        __syncthreads();
        #pragma unroll
        for (int i = ty; i < 32; i += 8)
            wqkT[(size_t)(n0 + i) * 1024 + k0 + tx] = f2bf(sT[tx][i]);
    }
}

// ---------------------------------------------------------------------------
extern "C" void kernel_launch(void* const* d_in, const int* in_sizes, int n_in,
                              void* d_out, int out_size, void* d_ws, size_t ws_size,
                              hipStream_t stream)
{
    (void)in_sizes; (void)n_in; (void)out_size; (void)ws_size;
    const float* x    = (const float*)d_in[0];
    const float* Wqk  = (const float*)d_in[1];
    const float* Wv   = (const float*)d_in[2];
    const float* Wout = (const float*)d_in[3];
    const float* tau  = (const float*)d_in[4];

    // out_b = x_b @ (W_v @ Weff_b); v never materialized.
    // qk is computed TRANSPOSED (qkT = Wqk^T @ x^T, channel-major) so gram
    // needs no LDS transpose.
    // ws layout:
    //   xb     : 16384x1024  bf16 (32 MB)
    //   wqkT   : 1024x1024   bf16 ( 2 MB)
    //   wvb    : 1024x1024   bf16 ( 2 MB)
    //   qkT    : 1024x16384  bf16 (32 MB)
    //   partial: 16x32x4096  f32  ( 8 MB)
    //   attnT  : 32x4096     f32  (.5 MB)
    //   weffT  : 2x1024x1024 bf16 ( 4 MB)
    //   wfoldT : 2x1024x1024 bf16 ( 4 MB)
    unsigned short* xb     = (unsigned short*)d_ws;
    unsigned short* wqkT   = xb + (size_t)16384 * 1024;
    unsigned short* wvb    = wqkT + (size_t)1024 * 1024;
    unsigned short* qkT    = wvb + (size_t)1024 * 1024;
    float*          partial= (float*)(qkT + (size_t)16384 * 1024);
    float*          attnT  = partial + (size_t)16 * 32 * 4096;
    unsigned short* weffT  = (unsigned short*)(attnT + (size_t)32 * 4096);
    unsigned short* wfoldT = weffT + (size_t)2 * 1024 * 1024;

    cvt_all_kernel<<<18432, 256, 0, stream>>>(x, Wv, Wqk, xb, wvb, wqkT);

    // qkT = Wqk^T @ x^T: C[c][n], M=1024 (4 m-blks), N=16384 (64 n-blks).
    // swapBig=1: each XCD owns 8 contiguous n-blocks (token range); the 4
    // m-blocks per n-strip are adjacent in dispatch order (share B strip).
    gemm256_bt<1><<<256, 512, 0, stream>>>(
        wqkT, xb, (void*)qkT, 1024, 1024, 1024, 16384, 0, 0, 0, 4, 8, 1);

    gram_kernel<<<dim3(32, 16), 256, 0, stream>>>(qkT, partial);
    softmax_kernel<<<512, 256, 0, stream>>>(partial, tau, attnT);
    wefft_kernel<<<dim3(32, 16), 256, 0, stream>>>(attnT, Wout, weffT);

    // WfoldT_b[j][c'] = sum_i WeffT_b[j][i] * W_v[c'][i]: small, keep 128^2
    gemm_bt<1><<<128, 256, 0, stream>>>(
        weffT, wvb, (void*)wfoldT, 1024, 1024, 1024, 1024,
        (size_t)1024 * 1024, 0, (size_t)1024 * 1024, 8, 1);

    // out_b = x_b @ Wfold_b  (M=8192/z, N=1024, K=1024): 32 m x 4 n x 2 z = 256
    gemm256_bt<0><<<256, 512, 0, stream>>>(
        xb, wfoldT, d_out, 1024, 1024, 1024, 1024,
        (size_t)8192 * 1024, (size_t)1024 * 1024, (size_t)8192 * 1024, 4, 4, 0);
}